// Round 5
// baseline (295.480 us; speedup 1.0000x reference)
//
#include <hip/hip_runtime.h>

// LSTM: B=4096, T=1024, I=8, H=4. fp32.
// R9 (terminal exact-math edit): og/rc-split feedback on the R8 base.
// Model (fits R5=277, R6=287, R7=458, R8=277 cyc/step): cycle = 4 trans
// dependent levels x ~58 cyc exposed + ~10 VALU levels x ~5 (hidden under
// trans). VALU trims are nearly free (R8: -2 levels -> -0.4us); only trans
// levels or the last VALU levels NOT hidden matter.
// R9 removes the h-materialization level: feedback a = g + sum w_k*og_k -
// 2*sum (w_k*og_k)*rc_k. partial/md_k depend only on og (ready ~120cyc
// before rc -> true off-cycle fill under the c-pair). On-cycle after rc:
// bcast rc (1) + fma tree (3) = 4 levels, vs R8's h-fma+bcast+tree = 5.
// Unlike R6: same activation block as R5/R8, prep consumes ONLY og, no
// s-carry, no extra on-cycle fma.
// Pre-registered: ~115.5 clean / ~122 if scheduler serializes / null ->
// 4-trans floor confirmed, playbook closed.
// Lane layout: 4 lanes/batch elem; lane j owns hidden j, gate rows
// {j,4+j,8+j,12+j} (PyTorch i,f,g,o). Broadcast via DPP quad_perm.

#define TT 1024
#define II 8
#define CHUNK 32
#define NCHUNK (TT / CHUNK)  // 32
#define ROW (CHUNK * II)     // 256 floats x per stream per chunk
#define SPAD 4

#define L2E 1.4426950408889634f
#define SIG_SCALE (-L2E)       // i,f,o rows
#define G_SCALE (2.0f * L2E)   // g row

typedef float v2f __attribute__((ext_vector_type(2)));

template <int CTRL>
__device__ __forceinline__ float dppf(float v) {
  return __int_as_float(
      __builtin_amdgcn_mov_dpp(__float_as_int(v), CTRL, 0xF, 0xF, true));
}

__device__ __forceinline__ float ex2(float x) {
  return __builtin_amdgcn_exp2f(x);
}
__device__ __forceinline__ float rcp(float x) {
  return __builtin_amdgcn_rcpf(x);
}

#define GLOAD_LDS16(gp, lp)                                   \
  __builtin_amdgcn_global_load_lds(                           \
      (const __attribute__((address_space(1))) void*)(gp),    \
      (__attribute__((address_space(3))) void*)(lp), 16, 0, 0)

__global__ __launch_bounds__(128, 1) void lstm_fused(
    const float* __restrict__ x, const float* __restrict__ W_ih,
    const float* __restrict__ W_hh, const float* __restrict__ b_ih,
    const float* __restrict__ b_hh, const float* __restrict__ fc_w,
    const float* __restrict__ fc_b, float* __restrict__ out, int B) {
  const int tid = threadIdx.x;
  const int wave = tid >> 6;
  const int lane = tid & 63;
  const int j = lane & 3;
  const int grp = lane >> 2;
  const int b = blockIdx.x * 16 + grp;

  __shared__ float xs0[16][ROW + SPAD];
  __shared__ float xs1[16][ROW + SPAD];
  // pre-act ring: [step][stream][j*4 + gate] — lane rw one contiguous float4;
  // wave touches 1KB stride-1 per step (2-way bank alias = free).
  __shared__ float pa0[CHUNK][16][16];
  __shared__ float pa1[CHUNK][16][16];

  if (wave == 0) {
    // ---------------- producer ----------------
    v2f wih01[II], wih23[II];
    v2f bias01, bias23;
#pragma unroll
    for (int k = 0; k < II; ++k) {
      wih01[k] = v2f{SIG_SCALE * W_ih[(0 * 4 + j) * II + k],
                     SIG_SCALE * W_ih[(1 * 4 + j) * II + k]};
      wih23[k] = v2f{G_SCALE * W_ih[(2 * 4 + j) * II + k],
                     SIG_SCALE * W_ih[(3 * 4 + j) * II + k]};
    }
    bias01 = v2f{SIG_SCALE * (b_ih[0 * 4 + j] + b_hh[0 * 4 + j]),
                 SIG_SCALE * (b_ih[1 * 4 + j] + b_hh[1 * 4 + j])};
    bias23 = v2f{G_SCALE * (b_ih[2 * 4 + j] + b_hh[2 * 4 + j]),
                 SIG_SCALE * (b_ih[3 * 4 + j] + b_hh[3 * 4 + j])};

    const size_t blockBase = (size_t)blockIdx.x * 16;

    auto issue = [&](float(*xs)[ROW + SPAD], int t0) {
#pragma unroll
      for (int s = 0; s < 16; ++s) {
        const float* gp =
            x + (blockBase + s) * (TT * II) + (size_t)t0 * II + lane * 4;
        GLOAD_LDS16(gp, &xs[s][0]);
      }
    };

    auto produce = [&](float(*pa)[16][16], const float(*xs)[ROW + SPAD]) {
      const float* row = &xs[grp][0];
#pragma unroll 8
      for (int u = 0; u < CHUNK; ++u) {
        const float4 xa = *(const float4*)(row + u * 8);
        const float4 xb = *(const float4*)(row + u * 8 + 4);
        v2f a01 = bias01, a23 = bias23;
#define XFMA(k, val)                                    \
  {                                                     \
    v2f xv = v2f{(val), (val)};                         \
    a01 = __builtin_elementwise_fma(wih01[k], xv, a01); \
    a23 = __builtin_elementwise_fma(wih23[k], xv, a23); \
  }
        XFMA(0, xa.x) XFMA(1, xa.y) XFMA(2, xa.z) XFMA(3, xa.w)
        XFMA(4, xb.x) XFMA(5, xb.y) XFMA(6, xb.z) XFMA(7, xb.w)
#undef XFMA
        *(float4*)&pa[u][grp][j * 4] = float4{a01.x, a01.y, a23.x, a23.y};
      }
    };

    issue(xs0, 0);
    issue(xs1, CHUNK);
    produce(pa0, xs0);
    __syncthreads();

    for (int ck = 0; ck < NCHUNK; ++ck) {
      if (ck + 1 < NCHUNK)
        produce(((ck + 1) & 1) ? pa1 : pa0, ((ck + 1) & 1) ? xs1 : xs0);
      if (ck + 2 < NCHUNK) issue((ck & 1) ? xs1 : xs0, (ck + 2) * CHUNK);
      __syncthreads();
    }
  } else {
    // ---------------- consumer (serial scan) ----------------
    // W_hh rows pre-scaled to match the producer's pre-act domain.
    v2f whh01[4], whh23[4];
#pragma unroll
    for (int k = 0; k < 4; ++k) {
      whh01[k] = v2f{SIG_SCALE * W_hh[(0 * 4 + j) * 4 + k],
                     SIG_SCALE * W_hh[(1 * 4 + j) * 4 + k]};
      whh23[k] = v2f{G_SCALE * W_hh[(2 * 4 + j) * 4 + k],
                     SIG_SCALE * W_hh[(3 * 4 + j) * 4 + k]};
    }
    // Carried state: c2 = 2*log2e*c, rc = (1-tanh(c))/2, og = sig(o).
    // og=0 makes the first step's feedback exactly zero regardless of rc.
    float c2 = 0.0f, rc = 0.25f, og = 0.0f;

    auto step = [&](float4 g) {
      // ---- OFF-CYCLE prep: depends only on og (ready ~120cyc before rc).
      // a(t+1) = [g + sum m_k] + sum (-2 m_k) rc_k,  m_k = w_k * og_k.
      const float o0 = dppf<0x00>(og), o1 = dppf<0x55>(og);
      const float o2 = dppf<0xAA>(og), o3 = dppf<0xFF>(og);
      const v2f m01_0 = whh01[0] * o0, m01_1 = whh01[1] * o1;
      const v2f m01_2 = whh01[2] * o2, m01_3 = whh01[3] * o3;
      const v2f m23_0 = whh23[0] * o0, m23_1 = whh23[1] * o1;
      const v2f m23_2 = whh23[2] * o2, m23_3 = whh23[3] * o3;
      const v2f p01 =
          (v2f{g.x, g.y} + (m01_0 + m01_1)) + (m01_2 + m01_3);  // partial
      const v2f p23 = (v2f{g.z, g.w} + (m23_0 + m23_1)) + (m23_2 + m23_3);
      const v2f md01_0 = -2.0f * m01_0, md01_1 = -2.0f * m01_1;
      const v2f md01_2 = -2.0f * m01_2, md01_3 = -2.0f * m01_3;
      const v2f md23_0 = -2.0f * m23_0, md23_1 = -2.0f * m23_1;
      const v2f md23_2 = -2.0f * m23_2, md23_3 = -2.0f * m23_3;
      // ---- ON-CYCLE from rc: bcast (1) + tree (3) -> a, then activations.
      const float r0 = dppf<0x00>(rc), r1 = dppf<0x55>(rc);
      const float r2 = dppf<0xAA>(rc), r3 = dppf<0xFF>(rc);
      v2f t01 = __builtin_elementwise_fma(md01_0, v2f{r0, r0}, p01);
      t01 = __builtin_elementwise_fma(md01_1, v2f{r1, r1}, t01);
      v2f u01 = md01_2 * v2f{r2, r2};
      u01 = __builtin_elementwise_fma(md01_3, v2f{r3, r3}, u01);
      const v2f a01 = t01 + u01;  // {i', f'} (scaled -log2e)
      v2f t23 = __builtin_elementwise_fma(md23_0, v2f{r0, r0}, p23);
      t23 = __builtin_elementwise_fma(md23_1, v2f{r1, r1}, t23);
      v2f u23 = md23_2 * v2f{r2, r2};
      u23 = __builtin_elementwise_fma(md23_3, v2f{r3, r3}, u23);
      const v2f a23 = t23 + u23;  // {g' (2log2e), o' (-log2e)}
      // activations (exp2 domain, hw ex2+rcp — accuracy-critical)
      const float ig = rcp(1.0f + ex2(a01.x));  // sig(i)
      const float fg = rcp(1.0f + ex2(a01.y));  // sig(f)
      const float rg = rcp(1.0f + ex2(a23.x));  // (1-tanh(g))/2
      og = rcp(1.0f + ex2(a23.y));              // sig(o)
      const float gg2 = fmaf(rg, -2.0f * G_SCALE, G_SCALE);  // 2log2e*tanh(g)
      const float fc = fg * c2;  // overlaps gg2's fma
      c2 = fmaf(ig, gg2, fc);
      rc = rcp(1.0f + ex2(c2));  // (1-tanh(c))/2
    };

    __syncthreads();

    for (int ck = 0; ck < NCHUNK; ++ck) {
      const float(*pa)[16][16] = (ck & 1) ? pa1 : pa0;
      const float* base = &pa[0][grp][j * 4];

      float4 ra[8], rb[8];
#define LOADB(r, u0)                                                \
  {                                                                 \
    _Pragma("unroll") for (int k = 0; k < 8; ++k) (r)[k] =          \
        *(const float4*)(base + (u0 + k) * 256);                    \
  }
#define COMP8(r)                                   \
  { _Pragma("unroll") for (int k = 0; k < 8; ++k) step((r)[k]); }

      LOADB(ra, 0)
      LOADB(rb, 8)
      COMP8(ra)
      LOADB(ra, 16)
      COMP8(rb)
      LOADB(rb, 24)
      COMP8(ra)
      COMP8(rb)
#undef LOADB
#undef COMP8
      __syncthreads();
    }

    // final FC: out[b] = sum_j h_j * fc_w[j] + fc_b,  h = og * tanh(c)
    const float h = og * fmaf(rc, -2.0f, 1.0f);
    float v = h * fc_w[j];
    v += dppf<0xB1>(v);  // quad_perm [1,0,3,2]
    v += dppf<0x4E>(v);  // quad_perm [2,3,0,1]
    if (j == 0 && b < B) out[b] = v + fc_b[0];
  }
}

extern "C" void kernel_launch(void* const* d_in, const int* in_sizes, int n_in,
                              void* d_out, int out_size, void* d_ws,
                              size_t ws_size, hipStream_t stream) {
  const float* x = (const float*)d_in[0];
  const float* W_ih = (const float*)d_in[1];
  const float* W_hh = (const float*)d_in[2];
  const float* b_ih = (const float*)d_in[3];
  const float* b_hh = (const float*)d_in[4];
  const float* fc_w = (const float*)d_in[5];
  const float* fc_b = (const float*)d_in[6];
  float* out = (float*)d_out;

  const int B = in_sizes[0] / (TT * II);
  const int nblocks = (B + 15) / 16;
  lstm_fused<<<nblocks, 128, 0, stream>>>(x, W_ih, W_hh, b_ih, b_hh, fc_w,
                                          fc_b, out, B);
}

// Round 6
// 261.616 us; speedup vs baseline: 1.1294x; 1.1294x over previous
//
#include <hip/hip_runtime.h>

// LSTM: B=4096, T=1024, I=8, H=4. fp32.
// R10 = R8 restored (best measured: 117.7us/dispatch, absmax 0.0). This is
// the terminal kernel; the session's latency floor.
//
// Why this is the floor (R5-R9 evidence):
//  - Wall = one stream's serial scan: 1024 steps x 277 cyc = 118us. Not a
//    memory/compute roofline (HBM 7%, VALU 22%) - a dependency-latency wall.
//  - Chain = 4 transcendental levels (ex2->rcp for gates, ex2->rcp for
//    tanh(c)) ~230 cyc + ~12 VALU levels mostly hidden under trans latency
//    (R8: -2 VALU levels -> -0.4us; free but irrelevant).
//  - Poly replacement of rcp (R7): deg-8 needed for 2e-7 error (1024-step
//    amplification ~4000x) -> 12 dense VALU levels > the rcp it replaces:
//    458 cyc/step, absmax 9.8e-4. Falsified.
//  - Off-cycle prep under the c-chain (R6: 287, R9: 365 cyc/step): hipcc's
//    in-order list scheduler places og-dependent prep ON the rc->a critical
//    segment; it will not software-pipeline across recurrence steps at HIP
//    level. Falsified twice with increasing downside.
//  - Time-parallel (Picard K~8 sweeps): forfeits 16-stream lane sharing,
//    ~37 instrs/stream-step issue-bound ~126us chip-wide. Costed out.
//
// Structure: producer/consumer wave split (128 thr). Producer: global_load_lds
// x-staging + input projection -> double-buffered LDS pre-act ring, pre-acts
// PRE-SCALED for exp2-domain activations (i,f,o rows by -log2e; g by 2log2e).
// Consumer: serial scan, register-batched ds_read_b128 ping-pong, hw ex2/rcp
// activations (accuracy-critical), c carried as c2 = 2log2e*c.
// R8's two free trims kept: depth-3 W_hh tree; c2 = fma(ig,gg2,fg*c2).
// Lane layout: 4 lanes/batch elem; lane j owns hidden j, gate rows
// {j,4+j,8+j,12+j} (PyTorch i,f,g,o). h-broadcast via DPP quad_perm.

#define TT 1024
#define II 8
#define CHUNK 32
#define NCHUNK (TT / CHUNK)  // 32
#define ROW (CHUNK * II)     // 256 floats x per stream per chunk
#define SPAD 4

#define L2E 1.4426950408889634f
#define SIG_SCALE (-L2E)       // i,f,o rows
#define G_SCALE (2.0f * L2E)   // g row

typedef float v2f __attribute__((ext_vector_type(2)));

template <int CTRL>
__device__ __forceinline__ float dppf(float v) {
  return __int_as_float(
      __builtin_amdgcn_mov_dpp(__float_as_int(v), CTRL, 0xF, 0xF, true));
}

__device__ __forceinline__ float ex2(float x) {
  return __builtin_amdgcn_exp2f(x);
}
__device__ __forceinline__ float rcp(float x) {
  return __builtin_amdgcn_rcpf(x);
}

#define GLOAD_LDS16(gp, lp)                                   \
  __builtin_amdgcn_global_load_lds(                           \
      (const __attribute__((address_space(1))) void*)(gp),    \
      (__attribute__((address_space(3))) void*)(lp), 16, 0, 0)

__global__ __launch_bounds__(128, 1) void lstm_fused(
    const float* __restrict__ x, const float* __restrict__ W_ih,
    const float* __restrict__ W_hh, const float* __restrict__ b_ih,
    const float* __restrict__ b_hh, const float* __restrict__ fc_w,
    const float* __restrict__ fc_b, float* __restrict__ out, int B) {
  const int tid = threadIdx.x;
  const int wave = tid >> 6;
  const int lane = tid & 63;
  const int j = lane & 3;
  const int grp = lane >> 2;
  const int b = blockIdx.x * 16 + grp;

  __shared__ float xs0[16][ROW + SPAD];
  __shared__ float xs1[16][ROW + SPAD];
  // pre-act ring: [step][stream][j*4 + gate] — lane rw one contiguous float4;
  // wave touches 1KB stride-1 per step (2-way bank alias = free).
  __shared__ float pa0[CHUNK][16][16];
  __shared__ float pa1[CHUNK][16][16];

  if (wave == 0) {
    // ---------------- producer ----------------
    v2f wih01[II], wih23[II];
    v2f bias01, bias23;
#pragma unroll
    for (int k = 0; k < II; ++k) {
      wih01[k] = v2f{SIG_SCALE * W_ih[(0 * 4 + j) * II + k],
                     SIG_SCALE * W_ih[(1 * 4 + j) * II + k]};
      wih23[k] = v2f{G_SCALE * W_ih[(2 * 4 + j) * II + k],
                     SIG_SCALE * W_ih[(3 * 4 + j) * II + k]};
    }
    bias01 = v2f{SIG_SCALE * (b_ih[0 * 4 + j] + b_hh[0 * 4 + j]),
                 SIG_SCALE * (b_ih[1 * 4 + j] + b_hh[1 * 4 + j])};
    bias23 = v2f{G_SCALE * (b_ih[2 * 4 + j] + b_hh[2 * 4 + j]),
                 SIG_SCALE * (b_ih[3 * 4 + j] + b_hh[3 * 4 + j])};

    const size_t blockBase = (size_t)blockIdx.x * 16;

    auto issue = [&](float(*xs)[ROW + SPAD], int t0) {
#pragma unroll
      for (int s = 0; s < 16; ++s) {
        const float* gp =
            x + (blockBase + s) * (TT * II) + (size_t)t0 * II + lane * 4;
        GLOAD_LDS16(gp, &xs[s][0]);
      }
    };

    auto produce = [&](float(*pa)[16][16], const float(*xs)[ROW + SPAD]) {
      const float* row = &xs[grp][0];
#pragma unroll 8
      for (int u = 0; u < CHUNK; ++u) {
        const float4 xa = *(const float4*)(row + u * 8);
        const float4 xb = *(const float4*)(row + u * 8 + 4);
        v2f a01 = bias01, a23 = bias23;
#define XFMA(k, val)                                    \
  {                                                     \
    v2f xv = v2f{(val), (val)};                         \
    a01 = __builtin_elementwise_fma(wih01[k], xv, a01); \
    a23 = __builtin_elementwise_fma(wih23[k], xv, a23); \
  }
        XFMA(0, xa.x) XFMA(1, xa.y) XFMA(2, xa.z) XFMA(3, xa.w)
        XFMA(4, xb.x) XFMA(5, xb.y) XFMA(6, xb.z) XFMA(7, xb.w)
#undef XFMA
        *(float4*)&pa[u][grp][j * 4] = float4{a01.x, a01.y, a23.x, a23.y};
      }
    };

    issue(xs0, 0);
    issue(xs1, CHUNK);
    produce(pa0, xs0);
    __syncthreads();

    for (int ck = 0; ck < NCHUNK; ++ck) {
      if (ck + 1 < NCHUNK)
        produce(((ck + 1) & 1) ? pa1 : pa0, ((ck + 1) & 1) ? xs1 : xs0);
      if (ck + 2 < NCHUNK) issue((ck & 1) ? xs1 : xs0, (ck + 2) * CHUNK);
      __syncthreads();
    }
  } else {
    // ---------------- consumer (serial scan) ----------------
    // W_hh rows pre-scaled to match the producer's pre-act domain.
    v2f whh01[4], whh23[4];
#pragma unroll
    for (int k = 0; k < 4; ++k) {
      whh01[k] = v2f{SIG_SCALE * W_hh[(0 * 4 + j) * 4 + k],
                     SIG_SCALE * W_hh[(1 * 4 + j) * 4 + k]};
      whh23[k] = v2f{G_SCALE * W_hh[(2 * 4 + j) * 4 + k],
                     SIG_SCALE * W_hh[(3 * 4 + j) * 4 + k]};
    }
    float h = 0.0f, c2 = 0.0f;  // c2 = 2*log2e * c

    auto step = [&](float4 g) {
      const float h0 = dppf<0x00>(h);
      const float h1 = dppf<0x55>(h);
      const float h2 = dppf<0xAA>(h);
      const float h3 = dppf<0xFF>(h);
      // depth-3 tree after bcast: ((g+w0h0)+w1h1) + (w2h2 fma w3h3)
      v2f t01 =
          __builtin_elementwise_fma(whh01[0], v2f{h0, h0}, v2f{g.x, g.y});
      t01 = __builtin_elementwise_fma(whh01[1], v2f{h1, h1}, t01);
      v2f u01 = whh01[2] * v2f{h2, h2};
      u01 = __builtin_elementwise_fma(whh01[3], v2f{h3, h3}, u01);
      const v2f a01 = t01 + u01;  // {i', f'} (scaled -log2e)
      v2f t23 =
          __builtin_elementwise_fma(whh23[0], v2f{h0, h0}, v2f{g.z, g.w});
      t23 = __builtin_elementwise_fma(whh23[1], v2f{h1, h1}, t23);
      v2f u23 = whh23[2] * v2f{h2, h2};
      u23 = __builtin_elementwise_fma(whh23[3], v2f{h3, h3}, u23);
      const v2f a23 = t23 + u23;  // {g' (2log2e), o' (-log2e)}
      // activations (exp2 domain, hw ex2+rcp — accuracy-critical)
      const float ig = rcp(1.0f + ex2(a01.x));  // sig(i)
      const float fg = rcp(1.0f + ex2(a01.y));  // sig(f)
      const float rg = rcp(1.0f + ex2(a23.x));  // (1-tanh(g))/2
      const float og = rcp(1.0f + ex2(a23.y));  // sig(o)
      const float gg2 = fmaf(rg, -2.0f * G_SCALE, G_SCALE);  // 2log2e*tanh(g)
      // rebalance: fg*c2 overlaps gg2's fma
      const float fc = fg * c2;
      c2 = fmaf(ig, gg2, fc);
      const float rc = rcp(1.0f + ex2(c2));  // (1-tanh(c))/2
      const float m2og = -2.0f * og;         // off-chain
      h = fmaf(rc, m2og, og);                // og*tanh(c)
    };

    __syncthreads();

    for (int ck = 0; ck < NCHUNK; ++ck) {
      const float(*pa)[16][16] = (ck & 1) ? pa1 : pa0;
      const float* base = &pa[0][grp][j * 4];

      float4 ra[8], rb[8];
#define LOADB(r, u0)                                                \
  {                                                                 \
    _Pragma("unroll") for (int k = 0; k < 8; ++k) (r)[k] =          \
        *(const float4*)(base + (u0 + k) * 256);                    \
  }
#define COMP8(r)                                   \
  { _Pragma("unroll") for (int k = 0; k < 8; ++k) step((r)[k]); }

      LOADB(ra, 0)
      LOADB(rb, 8)
      COMP8(ra)
      LOADB(ra, 16)
      COMP8(rb)
      LOADB(rb, 24)
      COMP8(ra)
      COMP8(rb)
#undef LOADB
#undef COMP8
      __syncthreads();
    }

    // final FC: out[b] = sum_j h_j * fc_w[j] + fc_b
    float v = h * fc_w[j];
    v += dppf<0xB1>(v);  // quad_perm [1,0,3,2]
    v += dppf<0x4E>(v);  // quad_perm [2,3,0,1]
    if (j == 0 && b < B) out[b] = v + fc_b[0];
  }
}

extern "C" void kernel_launch(void* const* d_in, const int* in_sizes, int n_in,
                              void* d_out, int out_size, void* d_ws,
                              size_t ws_size, hipStream_t stream) {
  const float* x = (const float*)d_in[0];
  const float* W_ih = (const float*)d_in[1];
  const float* W_hh = (const float*)d_in[2];
  const float* b_ih = (const float*)d_in[3];
  const float* b_hh = (const float*)d_in[4];
  const float* fc_w = (const float*)d_in[5];
  const float* fc_b = (const float*)d_in[6];
  float* out = (float*)d_out;

  const int B = in_sizes[0] / (TT * II);
  const int nblocks = (B + 15) / 16;
  lstm_fused<<<nblocks, 128, 0, stream>>>(x, W_ih, W_hh, b_ih, b_hh, fc_w,
                                          fc_b, out, B);
}